// Round 1
// baseline (1887.260 us; speedup 1.0000x reference)
//
#include <hip/hip_runtime.h>
#include <hip/hip_bf16.h>

typedef unsigned short ushort_t;
typedef unsigned int   uint_t;

#define B_    2
#define R_    8192
#define C_    64
#define HW_   256
#define S_    64
#define KRD_  16
#define NRAYS (B_*R_)
#define PLANE_ELEMS ((size_t)C_*HW_*HW_)       /* 4,194,304 floats per (plane,batch) */
#define TRP_ELEMS   ((size_t)HW_*HW_*C_)       /* 4,194,304 ushorts per (plane,batch) */
#define WS_PLANES_BYTES (6ull*B_*TRP_ELEMS*2)  /* 100,663,296 */
#define WS_WT_OFF   WS_PLANES_BYTES            /* transposed mlp weights, 8192 floats */
#define WAVES 2

__device__ __forceinline__ float bflo(uint_t u){ union{uint_t i;float f;} v; v.i = u << 16;         return v.f; }
__device__ __forceinline__ float bfhi(uint_t u){ union{uint_t i;float f;} v; v.i = u & 0xffff0000u; return v.f; }
__device__ __forceinline__ float sp(float x){ return fmaxf(x, 0.f) + __logf(1.f + __expf(-fabsf(x))); }
__device__ __forceinline__ ushort_t f2bf(float f){
    union{float f;uint_t u;} v; v.f = f;
    uint_t r = v.u + 0x7fffu + ((v.u >> 16) & 1u);   // RTNE
    return (ushort_t)(r >> 16);
}

// ---------------- Kernel A: transpose+quantize planes [C,H,W]f32 -> [H,W,C]bf16 ----------------
__global__ __launch_bounds__(256) void tr_planes(
    const float* __restrict__ p0, const float* __restrict__ p1, const float* __restrict__ p2,
    const float* __restrict__ p3, const float* __restrict__ p4, const float* __restrict__ p5,
    ushort_t* __restrict__ outp)
{
    const int blk = blockIdx.x;
    const int y = blk & 255, b = (blk >> 8) & 1, p = blk >> 9;
    const float* src = (p==0)?p0:(p==1)?p1:(p==2)?p2:(p==3)?p3:(p==4)?p4:p5;
    src += (size_t)b*PLANE_ELEMS + (size_t)y*HW_ + threadIdx.x;
    ushort_t* dst = outp + (size_t)(p*2+b)*TRP_ELEMS + ((size_t)y*HW_ + threadIdx.x)*C_;

    __attribute__((aligned(16))) ushort_t tmp[C_];
#pragma unroll
    for (int c = 0; c < C_; ++c)
        tmp[c] = f2bf(src[(size_t)c*HW_*HW_]);
#pragma unroll
    for (int k = 0; k < 8; ++k)
        reinterpret_cast<uint4*>(dst)[k] = reinterpret_cast<const uint4*>(tmp)[k];
}

// ---------------- Kernel A2: transpose mlp weights W[l][c][o] -> Wt[l][o][c] ----------------
__global__ __launch_bounds__(256) void tr_weights(const float* __restrict__ w, float* __restrict__ wt)
{
    int i = threadIdx.x + blockIdx.x*256;
    if (i < 2*64*64) {
        int l = i >> 12, o = (i >> 6) & 63, c = i & 63;
        wt[i] = w[l*4096 + c*64 + o];
    }
}

// ---------------- Kernel B: render ----------------
template<bool TR>
__global__ __launch_bounds__(WAVES*64) void render(
    const float* __restrict__ rays, const float* __restrict__ centers,
    const float* __restrict__ enc,  const float* __restrict__ nearp, const float* __restrict__ farp,
    const float* __restrict__ mlp_w, const float* __restrict__ mlp_b,
    const float* __restrict__ w_op,  const float* __restrict__ b_op,
    const float* __restrict__ w_col, const float* __restrict__ b_col,
    const float* __restrict__ bgc,
    const ushort_t* __restrict__ trp, const float* __restrict__ wt,
    const float* __restrict__ pxy,  const float* __restrict__ pyz,  const float* __restrict__ pzx,
    const float* __restrict__ pxyc, const float* __restrict__ pyzc, const float* __restrict__ pzxc,
    float* __restrict__ out)
{
    __shared__ float h_lds[WAVES][64][68];
    const int wave = threadIdx.x >> 6, lane = threadIdx.x & 63;
    const int gray = blockIdx.x * WAVES + wave;          // 0..16383
    const int b = gray >> 13;
    float* hrow = &h_lds[wave][lane][0];

    const float nr = nearp[gray], fr = farp[gray];
    const float rdx = rays[gray*3+0], rdy = rays[gray*3+1], rdz = rays[gray*3+2];
    const float rox = centers[gray*3+0], roy = centers[gray*3+1], roz = centers[gray*3+2];
    const float delta = (fr - nr) * (1.f/S_);
    const float t  = nr + (fr - nr) * ((lane + 0.5f) * (1.f/S_));
    const float px = rox + t*rdx, py = roy + t*rdy, pz = roz + t*rdz;

    // bilinear prep for the 3 plane mappings: (x,y), (y,z), (z,x)
    int pos[3]; float a00[3], a01[3], a10[3], a11[3];
    {
        float us[3] = {px, py, pz};
        float vs[3] = {py, pz, px};
#pragma unroll
        for (int p = 0; p < 3; ++p) {
            float x = (fminf(fmaxf(us[p],-1.f),1.f) + 1.f) * 127.5f;
            float y = (fminf(fmaxf(vs[p],-1.f),1.f) + 1.f) * 127.5f;
            int x0 = (int)floorf(x); x0 = x0 < 0 ? 0 : (x0 > 254 ? 254 : x0);
            int y0 = (int)floorf(y); y0 = y0 < 0 ? 0 : (y0 > 254 ? 254 : y0);
            float wx = x - (float)x0, wy = y - (float)y0;
            pos[p] = y0*HW_ + x0;
            a00[p] = (1.f-wx)*(1.f-wy); a01[p] = wx*(1.f-wy);
            a10[p] = (1.f-wx)*wy;       a11[p] = wx*wy;
        }
    }

    // sample a plane triple (pbase=0 density, pbase=3 color) into this lane's LDS row
    auto sample3 = [&](int pbase, const float* f0, const float* f1, const float* f2) {
        const ushort_t* tb[3];
        const float* fb[3] = {f0, f1, f2};
        if constexpr (TR) {
#pragma unroll
            for (int p = 0; p < 3; ++p)
                tb[p] = trp + (size_t)((pbase+p)*2 + b)*TRP_ELEMS + (size_t)pos[p]*64;
        }
        for (int c8 = 0; c8 < 8; ++c8) {
            float acc[8] = {0,0,0,0,0,0,0,0};
#pragma unroll
            for (int p = 0; p < 3; ++p) {
                if constexpr (TR) {
                    const ushort_t* q = tb[p] + c8*8;
                    union { uint4 v; uint_t u[4]; } q00, q01, q10, q11;
                    q00.v = *reinterpret_cast<const uint4*>(q);
                    q01.v = *reinterpret_cast<const uint4*>(q + 64);
                    q10.v = *reinterpret_cast<const uint4*>(q + 64*HW_);
                    q11.v = *reinterpret_cast<const uint4*>(q + 64*HW_ + 64);
#pragma unroll
                    for (int j = 0; j < 4; ++j) {
                        acc[2*j]   += a00[p]*bflo(q00.u[j]) + a01[p]*bflo(q01.u[j])
                                    + a10[p]*bflo(q10.u[j]) + a11[p]*bflo(q11.u[j]);
                        acc[2*j+1] += a00[p]*bfhi(q00.u[j]) + a01[p]*bfhi(q01.u[j])
                                    + a10[p]*bfhi(q10.u[j]) + a11[p]*bfhi(q11.u[j]);
                    }
                } else {
#pragma unroll
                    for (int j = 0; j < 8; ++j) {
                        const float* q = fb[p] + (size_t)(c8*8+j)*(HW_*HW_) + pos[p];
                        acc[j] += a00[p]*q[0] + a01[p]*q[1] + a10[p]*q[HW_] + a11[p]*q[HW_+1];
                    }
                }
            }
            *reinterpret_cast<float4*>(&hrow[c8*8])   = make_float4(acc[0],acc[1],acc[2],acc[3]);
            *reinterpret_cast<float4*>(&hrow[c8*8+4]) = make_float4(acc[4],acc[5],acc[6],acc[7]);
        }
    };

    const size_t bOff = (size_t)b*PLANE_ELEMS;
    sample3(0, pxy + bOff, pyz + bOff, pzx + bOff);

    float h[64];
#pragma unroll
    for (int i = 0; i < 16; ++i) {
        float4 v = *reinterpret_cast<float4*>(&hrow[i*4]);
        h[4*i+0]=v.x; h[4*i+1]=v.y; h[4*i+2]=v.z; h[4*i+3]=v.w;
    }

    // 2-layer MLP; weights are wave-uniform -> scalar loads
#pragma unroll
    for (int l = 0; l < 2; ++l) {
        const float* Wl = TR ? (wt + l*4096) : (mlp_w + l*4096);
        const float* bl = mlp_b + l*64;
#pragma unroll 2
        for (int o = 0; o < 64; ++o) {
            float s0=0.f, s1=0.f, s2=0.f, s3=0.f;
            if constexpr (TR) {
                const float* wr = Wl + o*64;   // contiguous row of Wt
#pragma unroll
                for (int c = 0; c < 64; c += 4) {
                    s0 += h[c+0]*wr[c+0]; s1 += h[c+1]*wr[c+1];
                    s2 += h[c+2]*wr[c+2]; s3 += h[c+3]*wr[c+3];
                }
            } else {
#pragma unroll
                for (int c = 0; c < 64; c += 4) {
                    s0 += h[c+0]*Wl[(c+0)*64+o]; s1 += h[c+1]*Wl[(c+1)*64+o];
                    s2 += h[c+2]*Wl[(c+2)*64+o]; s3 += h[c+3]*Wl[(c+3)*64+o];
                }
            }
            hrow[o] = sp(bl[o] + ((s0+s1)+(s2+s3)));
        }
#pragma unroll
        for (int i = 0; i < 16; ++i) {
            float4 v = *reinterpret_cast<float4*>(&hrow[i*4]);
            h[4*i+0]=v.x; h[4*i+1]=v.y; h[4*i+2]=v.z; h[4*i+3]=v.w;
        }
    }

    // opacity
    float s0=0.f, s1=0.f, s2=0.f, s3=0.f;
#pragma unroll
    for (int c = 0; c < 64; c += 4) {
        s0 += h[c+0]*w_op[c+0]; s1 += h[c+1]*w_op[c+1];
        s2 += h[c+2]*w_op[c+2]; s3 += h[c+3]*w_op[c+3];
    }
    const float sigma = sp(b_op[0] + ((s0+s1)+(s2+s3)));
    const float sd = sigma * delta;

    // inclusive scan of sd across the wave (lane = sample)
    float csd = sd;
#pragma unroll
    for (int off = 1; off < 64; off <<= 1) {
        float n = __shfl_up(csd, off, 64);
        if (lane >= off) csd += n;
    }
    const float nlt = __shfl(csd, 63, 64);
    const float Tw  = __expf(sd - csd) * (1.f - __expf(-sd));   // T_i * alpha_i
    const float em  = __expf(-nlt);                              // 1 - mask

    // color features
    sample3(3, pxyc + bOff, pyzc + bOff, pzxc + bOff);
    const float* er = enc + (size_t)gray*64;
#pragma unroll
    for (int i = 0; i < 16; ++i) {
        float4 f = *reinterpret_cast<float4*>(&hrow[i*4]);
        h[4*i+0] += f.x + er[4*i+0];
        h[4*i+1] += f.y + er[4*i+1];
        h[4*i+2] += f.z + er[4*i+2];
        h[4*i+3] += f.w + er[4*i+3];
    }

    float ck[16] = {0,0,0,0,0,0,0,0,0,0,0,0,0,0,0,0};
#pragma unroll
    for (int c = 0; c < 64; ++c) {
        const float v = h[c];
#pragma unroll
        for (int k = 0; k < 16; ++k)
            ck[k] += v * w_col[c*16 + k];
    }

    float rl = Tw * t;
#pragma unroll
    for (int o = 32; o > 0; o >>= 1) rl += __shfl_xor(rl, o, 64);
#pragma unroll
    for (int k = 0; k < 16; ++k) {
        float v = (ck[k] + b_col[k]) * Tw;
#pragma unroll
        for (int o = 32; o > 0; o >>= 1) v += __shfl_xor(v, o, 64);
        ck[k] = v;
    }

    if (lane == 0) {
#pragma unroll
        for (int k = 0; k < 16; ++k)
            out[(size_t)gray*16 + k] = ck[k] + em * bgc[k];
        out[(size_t)NRAYS*16 + gray] = 1.f - em;   // mask
        out[(size_t)NRAYS*17 + gray] = rl;         // ray_len
    }
}

extern "C" void kernel_launch(void* const* d_in, const int* in_sizes, int n_in,
                              void* d_out, int out_size, void* d_ws, size_t ws_size,
                              hipStream_t stream)
{
    const float* rays    = (const float*)d_in[0];
    const float* centers = (const float*)d_in[1];
    const float* enc     = (const float*)d_in[2];
    const float* nearp   = (const float*)d_in[3];
    const float* farp    = (const float*)d_in[4];
    const float* xy      = (const float*)d_in[5];
    const float* yz      = (const float*)d_in[6];
    const float* zx      = (const float*)d_in[7];
    const float* xyc     = (const float*)d_in[8];
    const float* yzc     = (const float*)d_in[9];
    const float* zxc     = (const float*)d_in[10];
    const float* mlp_w   = (const float*)d_in[11];
    const float* mlp_b   = (const float*)d_in[12];
    const float* w_op    = (const float*)d_in[13];
    const float* b_op    = (const float*)d_in[14];
    const float* w_col   = (const float*)d_in[15];
    const float* b_col   = (const float*)d_in[16];
    const float* bg      = (const float*)d_in[17];
    float* out = (float*)d_out;

    const bool use_tr = ws_size >= (size_t)(WS_PLANES_BYTES + 8192*4);

    if (use_tr) {
        ushort_t* trp = (ushort_t*)d_ws;
        float* wt = (float*)((char*)d_ws + WS_WT_OFF);
        tr_planes<<<6*2*HW_, 256, 0, stream>>>(xy, yz, zx, xyc, yzc, zxc, trp);
        tr_weights<<<32, 256, 0, stream>>>(mlp_w, wt);
        render<true><<<NRAYS/WAVES, WAVES*64, 0, stream>>>(
            rays, centers, enc, nearp, farp, mlp_w, mlp_b, w_op, b_op,
            w_col, b_col, bg, trp, wt, xy, yz, zx, xyc, yzc, zxc, out);
    } else {
        render<false><<<NRAYS/WAVES, WAVES*64, 0, stream>>>(
            rays, centers, enc, nearp, farp, mlp_w, mlp_b, w_op, b_op,
            w_col, b_col, bg, (const ushort_t*)nullptr, (const float*)nullptr,
            xy, yz, zx, xyc, yzc, zxc, out);
    }
}